// Round 2
// baseline (1114.852 us; speedup 1.0000x reference)
//
#include <hip/hip_runtime.h>
#include <hip/hip_bf16.h>
#include <hip/hip_fp16.h>
#include <math.h>

// T=1024 time steps, S=512 sequences, D=32 features, K=64 states (= wave width)
#define TT 1024
#define SS 512
#define DD 32
#define KK 64

#define LOG2PI_F 1.8378770664093453f

// ---------------------------------------------------------------------------
// Workspace layout (d_ws):
//   [0, 64MB)              : p''[T,S,K] fp16  (max-shifted emission probs)
//   [64MB, +8B)            : double msum  (sum of per-(t,s) max log-emissions)
//   [+8B, +2KB)            : float seq_logd[S]
#define PBUF_BYTES ((size_t)TT * SS * KK * 2)

__global__ __launch_bounds__(64) void init_accum(double* msum) {
    if (threadIdx.x == 0) *msum = 0.0;
}

// ---------------------------------------------------------------------------
// Emission: one wave per (t,s) item batch; lane = state k.
// p''[t,s,k] = exp(logp - max_k logp);  msum += max_k logp  (telescopes into nll)
#define EM_WPB 4            // waves per block (256 threads)
#define EM_BLOCKS 2048      // 8192 waves total -> 64 items per wave
__global__ __launch_bounds__(EM_WPB * 64) void emission_kernel(
    const float* __restrict__ data,      // [T,S,D]
    const float* __restrict__ means,     // [K,D]
    const float* __restrict__ covars,    // [K,D]
    __half* __restrict__ pbuf,           // [T,S,K]
    double* __restrict__ msum)
{
    const int k = threadIdx.x & 63;
    const int wv = blockIdx.x * EM_WPB + (threadIdx.x >> 6);

    float w[DD], m[DD];
    float c0 = DD * LOG2PI_F;
#pragma unroll
    for (int d = 0; d < DD; ++d) {
        float c = covars[k * DD + d];
        w[d] = 1.0f / c;
        m[d] = means[k * DD + d];
        c0 += __logf(c);
    }

    const int items_per_wave = (TT * SS) / (EM_BLOCKS * EM_WPB);  // 64
    const int base = wv * items_per_wave;
    float macc = 0.0f;

    for (int i = 0; i < items_per_wave; ++i) {
        const int item = base + i;                      // = t*S + s
        const float4* xp = (const float4*)(data + (size_t)item * DD);
        float q0 = 0.0f, q1 = 0.0f;
#pragma unroll
        for (int d4 = 0; d4 < DD / 4; ++d4) {
            float4 x = xp[d4];
            float t0 = x.x - m[4 * d4 + 0]; q0 = fmaf(w[4 * d4 + 0] * t0, t0, q0);
            float t1 = x.y - m[4 * d4 + 1]; q1 = fmaf(w[4 * d4 + 1] * t1, t1, q1);
            float t2 = x.z - m[4 * d4 + 2]; q0 = fmaf(w[4 * d4 + 2] * t2, t2, q0);
            float t3 = x.w - m[4 * d4 + 3]; q1 = fmaf(w[4 * d4 + 3] * t3, t3, q1);
        }
        float logp = -0.5f * (q0 + q1 + c0);
        float mx = logp;
#pragma unroll
        for (int off = 32; off > 0; off >>= 1)
            mx = fmaxf(mx, __shfl_xor(mx, off, 64));
        pbuf[(size_t)item * KK + k] = __float2half(__expf(logp - mx));
        macc += mx;   // wave-uniform
    }
    if (k == 0) atomicAdd(msum, (double)macc);
}

// ---------------------------------------------------------------------------
// Sequential forward recursion. One wave per sequence; lane = state.
// Normalize (wave-reduce + log) only every 4th step: with max-shifted
// emissions, den'' per step >= ~1e-5, so 4 unnormalized steps stay >= ~1e-20,
// well above fp32 underflow; batch denominators telescope exactly.
__global__ __launch_bounds__(64) void hmm_seq(
    const __half* __restrict__ pbuf,     // [T,S,K]
    const float* __restrict__ initial,   // [K]
    const float* __restrict__ trans,     // [K,K]
    float* __restrict__ out_alpha,       // [S,K]
    float* __restrict__ seq_logd)        // [S]
{
    const int s = blockIdx.x;
    const int k = threadIdx.x;

    float acol[KK];                      // A[j][k]
#pragma unroll
    for (int j = 0; j < KK; ++j) acol[j] = trans[j * KK + k];

    __shared__ float alpha_sh[KK];

    float logd = 0.0f;

    // t = 0 (unnormalized; scale absorbed by batch normalize at t=3)
    float a = initial[k] * __half2float(pbuf[(size_t)s * KK + k]);
    float pn = __half2float(pbuf[((size_t)SS + s) * KK + k]);   // prefetch t=1
    alpha_sh[k] = a;
    __syncthreads();

    for (int t = 1; t < TT; ++t) {
        const float pc = pn;
        if (t + 1 < TT)
            pn = __half2float(pbuf[((size_t)(t + 1) * SS + s) * KK + k]);

        float s0 = 0.0f, s1 = 0.0f, s2 = 0.0f, s3 = 0.0f;
        float s4 = 0.0f, s5 = 0.0f, s6 = 0.0f, s7 = 0.0f;
        const float4* ash = (const float4*)alpha_sh;
#pragma unroll
        for (int j4 = 0; j4 < KK / 8; ++j4) {
            float4 av = ash[2 * j4];
            float4 bv = ash[2 * j4 + 1];
            s0 = fmaf(av.x, acol[8 * j4 + 0], s0);
            s1 = fmaf(av.y, acol[8 * j4 + 1], s1);
            s2 = fmaf(av.z, acol[8 * j4 + 2], s2);
            s3 = fmaf(av.w, acol[8 * j4 + 3], s3);
            s4 = fmaf(bv.x, acol[8 * j4 + 4], s4);
            s5 = fmaf(bv.y, acol[8 * j4 + 5], s5);
            s6 = fmaf(bv.z, acol[8 * j4 + 6], s6);
            s7 = fmaf(bv.w, acol[8 * j4 + 7], s7);
        }
        a = pc * (((s0 + s1) + (s2 + s3)) + ((s4 + s5) + (s6 + s7)));

        if ((t & 3) == 3) {
            float den = a;
#pragma unroll
            for (int off = 32; off > 0; off >>= 1)
                den += __shfl_xor(den, off, 64);
            logd += __logf(den);
            a *= (1.0f / den);
        }

        alpha_sh[k] = a;
        __syncthreads();
    }

    out_alpha[(size_t)s * KK + k] = a;   // t=1023 ends on a normalize step
    if (k == 0) seq_logd[s] = logd;
}

// ---------------------------------------------------------------------------
// nll = -( sum_s seq_logd[s] + msum )   (alpha rows normalized -> logsumexp
// of log(alpha)+log_denom is exactly log_denom)
__global__ __launch_bounds__(256) void finalize(
    const float* __restrict__ seq_logd, const double* __restrict__ msum,
    float* __restrict__ out_nll)
{
    float v = 0.0f;
    for (int j = threadIdx.x; j < SS; j += 256) v += seq_logd[j];
#pragma unroll
    for (int off = 32; off > 0; off >>= 1)
        v += __shfl_xor(v, off, 64);
    __shared__ float sh[4];
    if ((threadIdx.x & 63) == 0) sh[threadIdx.x >> 6] = v;
    __syncthreads();
    if (threadIdx.x == 0) {
        double total = (double)(sh[0] + sh[1] + sh[2] + sh[3]) + *msum;
        out_nll[0] = (float)(-total);
    }
}

extern "C" void kernel_launch(void* const* d_in, const int* in_sizes, int n_in,
                              void* d_out, int out_size, void* d_ws, size_t ws_size,
                              hipStream_t stream) {
    const float* data    = (const float*)d_in[0];  // [T,S,D]
    const float* initial = (const float*)d_in[1];  // [K]
    const float* trans   = (const float*)d_in[2];  // [K,K]
    const float* means   = (const float*)d_in[3];  // [K,D]
    const float* covars  = (const float*)d_in[4];  // [K,D]

    float* out_alpha = (float*)d_out;                    // [S,K]
    float* out_nll   = (float*)d_out + (size_t)SS * KK;  // 1 float

    __half* pbuf     = (__half*)d_ws;
    double* msum     = (double*)((char*)d_ws + PBUF_BYTES);
    float*  seq_logd = (float*)((char*)d_ws + PBUF_BYTES + 8);

    init_accum<<<1, 64, 0, stream>>>(msum);
    emission_kernel<<<EM_BLOCKS, EM_WPB * 64, 0, stream>>>(
        data, means, covars, pbuf, msum);
    hmm_seq<<<SS, 64, 0, stream>>>(pbuf, initial, trans, out_alpha, seq_logd);
    finalize<<<1, 256, 0, stream>>>(seq_logd, msum, out_nll);
}

// Round 3
// 627.975 us; speedup vs baseline: 1.7753x; 1.7753x over previous
//
#include <hip/hip_runtime.h>
#include <hip/hip_bf16.h>
#include <hip/hip_fp16.h>
#include <math.h>

// T=1024 time steps, S=512 sequences, D=32 features, K=64 states (= wave width)
#define TT 1024
#define SS 512
#define DD 32
#define KK 64

#define LOG2PI_F 1.8378770664093453f

// Workspace layout (d_ws):
//   [0, 64MB)        : p''[T,S,K] fp16 (max-shifted emission probs)
//   [+0, +32KB)      : float mpart[8192] (per-wave sums of max log-emissions)
//   [+32KB, +2KB)    : float seq_logd[S]
#define PBUF_BYTES ((size_t)TT * SS * KK * 2)
#define EM_WPB 4
#define EM_BLOCKS 2048
#define NWAVES (EM_BLOCKS * EM_WPB)   // 8192

typedef float v2f __attribute__((ext_vector_type(2)));

__device__ __forceinline__ v2f fma2(v2f a, v2f b, v2f c) {
#if __has_builtin(__builtin_elementwise_fma)
    return __builtin_elementwise_fma(a, b, c);
#else
    v2f r; r.x = fmaf(a.x, b.x, c.x); r.y = fmaf(a.y, b.y, c.y); return r;
#endif
}

// ---------------------------------------------------------------------------
// Emission: one wave per batch of 64 (t,s) items; lane = state k.
// p''[t,s,k] = exp(logp - max_k logp); mpart[wave] = sum of per-item maxes.
__global__ __launch_bounds__(EM_WPB * 64) void emission_kernel(
    const float* __restrict__ data,      // [T,S,D]
    const float* __restrict__ means,     // [K,D]
    const float* __restrict__ covars,    // [K,D]
    __half* __restrict__ pbuf,           // [T,S,K]
    float* __restrict__ mpart)           // [NWAVES]
{
    const int k  = threadIdx.x & 63;
    const int wv = blockIdx.x * EM_WPB + (threadIdx.x >> 6);

    v2f w2[DD / 2], m2[DD / 2];
    float c0 = DD * LOG2PI_F;
#pragma unroll
    for (int d = 0; d < DD; ++d) {
        float c = covars[k * DD + d];
        ((float*)w2)[d] = 1.0f / c;
        ((float*)m2)[d] = means[k * DD + d];
        c0 += __logf(c);
    }

    const int ipw = (TT * SS) / NWAVES;  // 64
    const int base = wv * ipw;
    float macc = 0.0f;

#pragma unroll 2
    for (int i = 0; i < ipw; ++i) {
        const int item = base + i;                     // = t*S + s
        const float4* xp = (const float4*)(data + (size_t)item * DD);
        v2f q0 = {0.0f, 0.0f}, q1 = {0.0f, 0.0f};
#pragma unroll
        for (int d4 = 0; d4 < DD / 4; ++d4) {
            float4 x = xp[d4];
            v2f xa; xa.x = x.x; xa.y = x.y;
            v2f xb; xb.x = x.z; xb.y = x.w;
            v2f ta = xa - m2[2 * d4];
            v2f tb = xb - m2[2 * d4 + 1];
            q0 = fma2(w2[2 * d4] * ta, ta, q0);
            q1 = fma2(w2[2 * d4 + 1] * tb, tb, q1);
        }
        float q = (q0.x + q0.y) + (q1.x + q1.y);
        float logp = -0.5f * (q + c0);
        float mx = logp;
#pragma unroll
        for (int off = 32; off > 0; off >>= 1)
            mx = fmaxf(mx, __shfl_xor(mx, off, 64));
        pbuf[(size_t)item * KK + k] = __float2half(__expf(logp - mx));
        macc += mx;   // wave-uniform
    }
    if (k == 0) mpart[wv] = macc;
}

// ---------------------------------------------------------------------------
// Sequential forward recursion. One wave per sequence; lane = state.
// Single-wave block => NO s_barrier needed: LDS ops from one wave execute
// in order; wave_barrier() is a zero-cost compiler scheduling fence. This
// keeps the 8-deep emission-prob prefetch in flight (a __syncthreads here
// would emit s_waitcnt vmcnt(0) and serialize on load latency — round-2 bug).
// Normalize (wave-reduce + log) only every 4th step: max-shifted emissions
// keep per-step den'' >= ~1e-5, so 4 raw steps stay >= ~1e-20 >> fp32 min.
__global__ __launch_bounds__(64) void hmm_seq(
    const __half* __restrict__ pbuf,     // [T,S,K]
    const float* __restrict__ initial,   // [K]
    const float* __restrict__ trans,     // [K,K]
    float* __restrict__ out_alpha,       // [S,K]
    float* __restrict__ seq_logd)        // [S]
{
    const int s = blockIdx.x;
    const int k = threadIdx.x;

    v2f acl[KK / 2];                     // pairs (A[2j][k], A[2j+1][k])
#pragma unroll
    for (int j = 0; j < KK / 2; ++j) {
        acl[j].x = trans[(2 * j) * KK + k];
        acl[j].y = trans[(2 * j + 1) * KK + k];
    }

    __shared__ __align__(16) float alpha_sh[KK];

    const __half* pp = pbuf + (size_t)s * KK + k;
    const size_t PST = (size_t)SS * KK;  // elements per time step

    __half pf[8];                        // 8-deep prefetch ring
#pragma unroll
    for (int i = 0; i < 8; ++i) pf[i] = pp[PST * i];

    const float init_k = initial[k];
    float logd = 0.0f;
    float a = 0.0f;

    for (int mblk = 0; mblk < TT / 8; ++mblk) {
#pragma unroll
        for (int i = 0; i < 8; ++i) {
            const int t = 8 * mblk + i;
            const float pc = __half2float(pf[i]);
            int tn = t + 8; if (tn >= TT) tn = TT - 1;   // clamped (uniform)
            pf[i] = pp[PST * (size_t)tn];

            if (mblk == 0 && i == 0) {
                a = init_k * pc;
            } else {
                const float4* ash4 = (const float4*)alpha_sh;
                v2f a0 = {0,0}, a1 = {0,0}, a2 = {0,0}, a3 = {0,0};
#pragma unroll
                for (int j4 = 0; j4 < KK / 4; ++j4) {
                    float4 av = ash4[j4];
                    v2f lo; lo.x = av.x; lo.y = av.y;
                    v2f hi; hi.x = av.z; hi.y = av.w;
                    if (j4 & 1) {
                        a2 = fma2(lo, acl[2 * j4], a2);
                        a3 = fma2(hi, acl[2 * j4 + 1], a3);
                    } else {
                        a0 = fma2(lo, acl[2 * j4], a0);
                        a1 = fma2(hi, acl[2 * j4 + 1], a1);
                    }
                }
                v2f sv = (a0 + a1) + (a2 + a3);
                a = pc * (sv.x + sv.y);
            }

            if ((t & 3) == 3) {
                float den = a;
#pragma unroll
                for (int off = 32; off > 0; off >>= 1)
                    den += __shfl_xor(den, off, 64);
                logd += __logf(den);
                a *= __builtin_amdgcn_rcpf(den);
            }

            alpha_sh[k] = a;
            __builtin_amdgcn_wave_barrier();   // order LDS write vs next reads
        }
    }

    out_alpha[(size_t)s * KK + k] = a;   // t=1023 ends on a normalize step
    if (k == 0) seq_logd[s] = logd;
}

// ---------------------------------------------------------------------------
// nll = -( sum_s seq_logd[s] + sum_w mpart[w] )
__global__ __launch_bounds__(256) void finalize(
    const float* __restrict__ seq_logd, const float* __restrict__ mpart,
    float* __restrict__ out_nll)
{
    float v = 0.0f;
    for (int j = threadIdx.x; j < NWAVES; j += 256) v += mpart[j];
    for (int j = threadIdx.x; j < SS; j += 256) v += seq_logd[j];
#pragma unroll
    for (int off = 32; off > 0; off >>= 1)
        v += __shfl_xor(v, off, 64);
    __shared__ float sh[4];
    if ((threadIdx.x & 63) == 0) sh[threadIdx.x >> 6] = v;
    __syncthreads();
    if (threadIdx.x == 0) {
        double total = ((double)sh[0] + sh[1]) + ((double)sh[2] + sh[3]);
        out_nll[0] = (float)(-total);
    }
}

extern "C" void kernel_launch(void* const* d_in, const int* in_sizes, int n_in,
                              void* d_out, int out_size, void* d_ws, size_t ws_size,
                              hipStream_t stream) {
    const float* data    = (const float*)d_in[0];  // [T,S,D]
    const float* initial = (const float*)d_in[1];  // [K]
    const float* trans   = (const float*)d_in[2];  // [K,K]
    const float* means   = (const float*)d_in[3];  // [K,D]
    const float* covars  = (const float*)d_in[4];  // [K,D]

    float* out_alpha = (float*)d_out;                    // [S,K]
    float* out_nll   = (float*)d_out + (size_t)SS * KK;  // 1 float

    __half* pbuf     = (__half*)d_ws;
    float*  mpart    = (float*)((char*)d_ws + PBUF_BYTES);
    float*  seq_logd = (float*)((char*)d_ws + PBUF_BYTES + NWAVES * sizeof(float));

    emission_kernel<<<EM_BLOCKS, EM_WPB * 64, 0, stream>>>(
        data, means, covars, pbuf, mpart);
    hmm_seq<<<SS, 64, 0, stream>>>(pbuf, initial, trans, out_alpha, seq_logd);
    finalize<<<1, 256, 0, stream>>>(seq_logd, mpart, out_nll);
}